// Round 9
// baseline (338.240 us; speedup 1.0000x reference)
//
#include <hip/hip_runtime.h>

#define LL 2048
#define EE 2048
#define DD 1024
#define NC 64    // chunks along L
#define CH 32    // chunk length (NC*CH == LL)

typedef short bf16x8 __attribute__((ext_vector_type(8)));
typedef float f32x4 __attribute__((ext_vector_type(4)));

__device__ inline float bf2f(unsigned short u) {
    union { unsigned u; float f; } v; v.u = ((unsigned)u) << 16; return v.f;
}
__device__ inline unsigned short f2bf(float f) {
    union { float f; unsigned u; } v; v.f = f;
    unsigned r = v.u + 0x7fff + ((v.u >> 16) & 1);
    return (unsigned short)(r >> 16);
}

__device__ inline void gload_lds16(const void* g, void* lds) {
    __builtin_amdgcn_global_load_lds(
        (const __attribute__((address_space(1))) unsigned int*)g,
        (__attribute__((address_space(3))) unsigned int*)lds, 16, 0, 0);
}

// ================= 256x256 8-phase counted-vmcnt GEMM (in_proj only) =================
template<int MODE, int BN, int STRIPE>
__global__ __launch_bounds__(512, 2)
void gemm8p(const unsigned short* __restrict__ A,
            const unsigned short* __restrict__ Bw,
            void* __restrict__ Cout,
            int M, int N, int K)
{
    constexpr int NREP = BN / 64;
    constexpr int RB   = BN / 128;
    constexpr int LH   = 2 + RB;
    constexpr int NSTRIP = BN / 4;

    extern __shared__ short lds[];
    short* Asm = lds;                    // [2buf][2kh][256][32]
    short* Bsm = lds + 2 * 2 * 256 * 32; // [2buf][2kh][BN][32]

    const int tid = threadIdx.x;
    const int w = tid >> 6, lane = tid & 63;
    const int wm = w >> 2, wn = w & 3;

    const int gx = N / BN;
    int lin = blockIdx.y * gx + blockIdx.x;
    const int k = lin & 7, loc = lin >> 3;
    const int bpc = STRIPE * gx;
    const int j = loc / bpc;
    const int wi = loc % bpc;
    const int my = (k + 8 * j) * STRIPE + wi / gx;
    const int nx = wi % gx;
    const long m0 = (long)my * 256;
    const long n0 = (long)nx * BN;

    const int g = (tid & 3) ^ ((tid >> 3) & 3);
    const int arow = tid >> 2;
    const unsigned short* Ag = A + (m0 + arow) * (long)K + g * 8;
    const unsigned short* Bg = Bw + (n0 + arow) * (long)K + g * 8;
    const int ldsrow = w * 16;

    auto stageA = [&](int buf, int kh, int jj, int kt) {
        gload_lds16(Ag + (long)jj * 128 * K + kt * 64 + kh * 32,
                    Asm + ((buf * 2 + kh) * 256 + jj * 128 + ldsrow) * 32);
    };
    auto stageB = [&](int buf, int kh, int jj, int kt) {
        gload_lds16(Bg + (long)jj * 128 * K + kt * 64 + kh * 32,
                    Bsm + ((buf * 2 + kh) * BN + jj * 128 + ldsrow) * 32);
    };

    f32x4 acc[8][NREP] = {};

    stageA(0, 0, 0, 0); stageA(0, 0, 1, 0);
#pragma unroll
    for (int jj = 0; jj < RB; ++jj) stageB(0, 0, jj, 0);
    stageA(0, 1, 0, 0); stageA(0, 1, 1, 0);
#pragma unroll
    for (int jj = 0; jj < RB; ++jj) stageB(0, 1, jj, 0);

    const int NT = K / 64;
    const int rr = lane & 15;
    const int sl = ((lane >> 4) ^ ((rr >> 1) & 3)) * 8;

    for (int t = 0; t < NT; ++t) {
        const int cur = t & 1, nxt = cur ^ 1;
        const bool more = (t + 1 < NT);

        asm volatile("s_waitcnt vmcnt(%0)" :: "i"(LH) : "memory");
        __builtin_amdgcn_s_barrier();

        const short* Ac0 = Asm + (cur * 2 + 0) * 256 * 32;
        const short* Bc0 = Bsm + (cur * 2 + 0) * BN * 32;
        if (more) { stageA(nxt, 0, 0, t + 1); stageA(nxt, 0, 1, t + 1); }
        bf16x8 a[4], b[NREP];
#pragma unroll
        for (int m = 0; m < 4; ++m)
            a[m] = *(const bf16x8*)&Ac0[(wm * 128 + m * 16 + rr) * 32 + sl];
#pragma unroll
        for (int n = 0; n < NREP; ++n)
            b[n] = *(const bf16x8*)&Bc0[(wn * NSTRIP + n * 16 + rr) * 32 + sl];
        __builtin_amdgcn_s_setprio(1);
#pragma unroll
        for (int m = 0; m < 4; ++m)
#pragma unroll
            for (int n = 0; n < NREP; ++n)
                acc[m][n] = __builtin_amdgcn_mfma_f32_16x16x32_bf16(a[m], b[n], acc[m][n], 0, 0, 0);
        __builtin_amdgcn_s_setprio(0);
        if (more) {
#pragma unroll
            for (int jj = 0; jj < RB; ++jj) stageB(nxt, 0, jj, t + 1);
        }
#pragma unroll
        for (int m = 0; m < 4; ++m)
            a[m] = *(const bf16x8*)&Ac0[(wm * 128 + 64 + m * 16 + rr) * 32 + sl];
        __builtin_amdgcn_s_setprio(1);
#pragma unroll
        for (int m = 0; m < 4; ++m)
#pragma unroll
            for (int n = 0; n < NREP; ++n)
                acc[4 + m][n] = __builtin_amdgcn_mfma_f32_16x16x32_bf16(a[m], b[n], acc[4 + m][n], 0, 0, 0);
        __builtin_amdgcn_s_setprio(0);

        if (more) { asm volatile("s_waitcnt vmcnt(%0)" :: "i"(LH) : "memory"); }
        else      { asm volatile("s_waitcnt vmcnt(0)" ::: "memory"); }
        __builtin_amdgcn_s_barrier();

        const short* Ac1 = Asm + (cur * 2 + 1) * 256 * 32;
        const short* Bc1 = Bsm + (cur * 2 + 1) * BN * 32;
        if (more) { stageA(nxt, 1, 0, t + 1); stageA(nxt, 1, 1, t + 1); }
#pragma unroll
        for (int m = 0; m < 4; ++m)
            a[m] = *(const bf16x8*)&Ac1[(wm * 128 + m * 16 + rr) * 32 + sl];
#pragma unroll
        for (int n = 0; n < NREP; ++n)
            b[n] = *(const bf16x8*)&Bc1[(wn * NSTRIP + n * 16 + rr) * 32 + sl];
        __builtin_amdgcn_s_setprio(1);
#pragma unroll
        for (int m = 0; m < 4; ++m)
#pragma unroll
            for (int n = 0; n < NREP; ++n)
                acc[m][n] = __builtin_amdgcn_mfma_f32_16x16x32_bf16(a[m], b[n], acc[m][n], 0, 0, 0);
        __builtin_amdgcn_s_setprio(0);
        if (more) {
#pragma unroll
            for (int jj = 0; jj < RB; ++jj) stageB(nxt, 1, jj, t + 1);
        }
#pragma unroll
        for (int m = 0; m < 4; ++m)
            a[m] = *(const bf16x8*)&Ac1[(wm * 128 + 64 + m * 16 + rr) * 32 + sl];
        __builtin_amdgcn_s_setprio(1);
#pragma unroll
        for (int m = 0; m < 4; ++m)
#pragma unroll
            for (int n = 0; n < NREP; ++n)
                acc[4 + m][n] = __builtin_amdgcn_mfma_f32_16x16x32_bf16(a[m], b[n], acc[4 + m][n], 0, 0, 0);
        __builtin_amdgcn_s_setprio(0);
    }

#pragma unroll
    for (int m = 0; m < 8; ++m) {
#pragma unroll
        for (int n = 0; n < NREP; ++n) {
#pragma unroll
            for (int r = 0; r < 4; ++r) {
                long row = m0 + wm * 128 + m * 16 + (lane >> 4) * 4 + r;
                long col = n0 + wn * NSTRIP + n * 16 + (lane & 15);
                float v = acc[m][n][r];
                if (MODE == 0) ((float*)Cout)[row * N + col] = v;
                else           ((unsigned short*)Cout)[row * N + col] = f2bf(v);
            }
        }
    }
}

// ========= m97-style 128x128 2-barrier GEMM (general M,N,K; bf16 out) =========
// 16KB LDS single-buffer, slot-XOR swizzle, ~3 blocks/CU -> cross-block TLP.
__global__ __launch_bounds__(256)
void gemm128(const unsigned short* __restrict__ A,
             const unsigned short* __restrict__ Bw,
             unsigned short* __restrict__ Cout,
             int M, int N, int K)
{
    __shared__ short As[128 * 32];
    __shared__ short Bs[128 * 32];
    const int tid = threadIdx.x;
    const int wave = tid >> 6, lane = tid & 63;
    const int wm = wave >> 1, wn = wave & 1;
    const long m0 = (long)blockIdx.y * 128;
    const long n0 = (long)blockIdx.x * 128;

    f32x4 acc[4][4] = {};

    const int srow = lane >> 2;
    const int g = (lane & 3) ^ ((srow >> 1) & 3);
    const int c0 = wave, c1 = wave + 4;

    for (int k0 = 0; k0 < K; k0 += 32) {
        gload_lds16(A + (m0 + c0 * 16 + srow) * (long)K + k0 + g * 8, &As[c0 * 16 * 32]);
        gload_lds16(A + (m0 + c1 * 16 + srow) * (long)K + k0 + g * 8, &As[c1 * 16 * 32]);
        gload_lds16(Bw + (n0 + c0 * 16 + srow) * (long)K + k0 + g * 8, &Bs[c0 * 16 * 32]);
        gload_lds16(Bw + (n0 + c1 * 16 + srow) * (long)K + k0 + g * 8, &Bs[c1 * 16 * 32]);
        __syncthreads();

        const int rr = lane & 15;
        const int sl = ((lane >> 4) ^ ((rr >> 1) & 3)) * 8;
        bf16x8 af[4], bfr[4];
#pragma unroll
        for (int m = 0; m < 4; ++m)
            af[m] = *(const bf16x8*)&As[(wm * 64 + m * 16 + rr) * 32 + sl];
#pragma unroll
        for (int n = 0; n < 4; ++n)
            bfr[n] = *(const bf16x8*)&Bs[(wn * 64 + n * 16 + rr) * 32 + sl];
#pragma unroll
        for (int m = 0; m < 4; ++m)
#pragma unroll
            for (int n = 0; n < 4; ++n)
                acc[m][n] = __builtin_amdgcn_mfma_f32_16x16x32_bf16(af[m], bfr[n], acc[m][n], 0, 0, 0);
        __syncthreads();
    }

#pragma unroll
    for (int m = 0; m < 4; ++m)
#pragma unroll
        for (int n = 0; n < 4; ++n)
#pragma unroll
            for (int r = 0; r < 4; ++r) {
                long row = m0 + wm * 64 + m * 16 + (lane >> 4) * 4 + r;
                long col = n0 + wn * 64 + n * 16 + (lane & 15);
                Cout[row * N + col] = f2bf(acc[m][n][r]);
            }
}

// ============ x_proj split-K GEMM: 128x128 tile, K-slice 512, kz 0..3 ============
__global__ __launch_bounds__(256)
void gemm_xp(const unsigned short* __restrict__ A,
             const unsigned short* __restrict__ Bw,
             float* __restrict__ Cout)
{
    __shared__ short As[128 * 32];
    __shared__ short Bs[128 * 32];
    const int tid = threadIdx.x;
    const int wave = tid >> 6, lane = tid & 63;
    const int wm = wave >> 1, wn = wave & 1;
    const long m0 = (long)blockIdx.x * 128;
    const int kz = blockIdx.y;
    float* out = Cout + (long)kz * 8192 * 128;

    f32x4 acc[4][4] = {};

    const int srow = lane >> 2;
    const int g = (lane & 3) ^ ((srow >> 1) & 3);
    const int c0 = wave, c1 = wave + 4;

    for (int k0 = kz * 512; k0 < kz * 512 + 512; k0 += 32) {
        gload_lds16(A + (m0 + c0 * 16 + srow) * 2048L + k0 + g * 8, &As[c0 * 16 * 32]);
        gload_lds16(A + (m0 + c1 * 16 + srow) * 2048L + k0 + g * 8, &As[c1 * 16 * 32]);
        gload_lds16(Bw + (c0 * 16 + srow) * 2048L + k0 + g * 8, &Bs[c0 * 16 * 32]);
        gload_lds16(Bw + (c1 * 16 + srow) * 2048L + k0 + g * 8, &Bs[c1 * 16 * 32]);
        __syncthreads();

        const int rr = lane & 15;
        const int sl = ((lane >> 4) ^ ((rr >> 1) & 3)) * 8;
        bf16x8 af[4], bfr[4];
#pragma unroll
        for (int m = 0; m < 4; ++m)
            af[m] = *(const bf16x8*)&As[(wm * 64 + m * 16 + rr) * 32 + sl];
#pragma unroll
        for (int n = 0; n < 4; ++n)
            bfr[n] = *(const bf16x8*)&Bs[(wn * 64 + n * 16 + rr) * 32 + sl];
#pragma unroll
        for (int m = 0; m < 4; ++m)
#pragma unroll
            for (int n = 0; n < 4; ++n)
                acc[m][n] = __builtin_amdgcn_mfma_f32_16x16x32_bf16(af[m], bfr[n], acc[m][n], 0, 0, 0);
        __syncthreads();
    }

#pragma unroll
    for (int m = 0; m < 4; ++m)
#pragma unroll
        for (int n = 0; n < 4; ++n)
#pragma unroll
            for (int r = 0; r < 4; ++r) {
                long row = m0 + wm * 64 + m * 16 + (lane >> 4) * 4 + r;
                long col = wn * 64 + n * 16 + (lane & 15);
                out[row * 128 + col] = acc[m][n][r];
            }
}

// sum 4 K-partials -> dbc f32; cols < 64 also -> dt bf16
__global__ void reduce_dbc(const float* __restrict__ part,
                           float* __restrict__ dbc,
                           unsigned short* __restrict__ dt)
{
    const long i = (long)blockIdx.x * 256 + threadIdx.x;
    float s = part[i] + part[i + 1048576] + part[i + 2 * 1048576] + part[i + 3 * 1048576];
    dbc[i] = s;
    const int c = (int)(i & 127);
    if (c < 64) dt[(i >> 7) * 64 + c] = f2bf(s);
}

// ===== dt_proj: light 128x128 2-phase GEMM, K=64 =====
__global__ __launch_bounds__(256)
void gemm_dt(const unsigned short* __restrict__ A,
             const unsigned short* __restrict__ Bw,
             const float* __restrict__ bias,
             unsigned short* __restrict__ Cout)
{
    __shared__ short As[128 * 32];
    __shared__ short Bs[128 * 32];
    const int tid = threadIdx.x;
    const int wave = tid >> 6, lane = tid & 63;
    const int wm = wave >> 1, wn = wave & 1;
    const long m0 = (long)blockIdx.y * 128;
    const long n0 = (long)blockIdx.x * 128;

    f32x4 acc[4][4] = {};

    const int srow = lane >> 2;
    const int g = (lane & 3) ^ ((srow >> 1) & 3);
    const int c0 = wave, c1 = wave + 4;

    for (int k0 = 0; k0 < 64; k0 += 32) {
        gload_lds16(A + (m0 + c0 * 16 + srow) * 64L + k0 + g * 8, &As[c0 * 16 * 32]);
        gload_lds16(A + (m0 + c1 * 16 + srow) * 64L + k0 + g * 8, &As[c1 * 16 * 32]);
        gload_lds16(Bw + (n0 + c0 * 16 + srow) * 64L + k0 + g * 8, &Bs[c0 * 16 * 32]);
        gload_lds16(Bw + (n0 + c1 * 16 + srow) * 64L + k0 + g * 8, &Bs[c1 * 16 * 32]);
        __syncthreads();

        const int rr = lane & 15;
        const int sl = ((lane >> 4) ^ ((rr >> 1) & 3)) * 8;
        bf16x8 af[4], bfr[4];
#pragma unroll
        for (int m = 0; m < 4; ++m)
            af[m] = *(const bf16x8*)&As[(wm * 64 + m * 16 + rr) * 32 + sl];
#pragma unroll
        for (int n = 0; n < 4; ++n)
            bfr[n] = *(const bf16x8*)&Bs[(wn * 64 + n * 16 + rr) * 32 + sl];
#pragma unroll
        for (int m = 0; m < 4; ++m)
#pragma unroll
            for (int n = 0; n < 4; ++n)
                acc[m][n] = __builtin_amdgcn_mfma_f32_16x16x32_bf16(af[m], bfr[n], acc[m][n], 0, 0, 0);
        __syncthreads();
    }

#pragma unroll
    for (int m = 0; m < 4; ++m)
#pragma unroll
        for (int n = 0; n < 4; ++n)
#pragma unroll
            for (int r = 0; r < 4; ++r) {
                long row = m0 + wm * 64 + m * 16 + (lane >> 4) * 4 + r;
                long col = n0 + wn * 64 + n * 16 + (lane & 15);
                float v = acc[m][n][r] + bias[col];
                float sp = (v > 20.f) ? v : log1pf(__expf(v));
                Cout[row * 2048 + col] = f2bf(sp);
            }
}

// ---- all f32->bf16 operand conversions in ONE launch ----
__device__ inline void cvt4(const float* __restrict__ in, unsigned short* __restrict__ out, long i) {
    float4 v = ((const float4*)in)[i];
    unsigned lo = (unsigned)f2bf(v.x) | ((unsigned)f2bf(v.y) << 16);
    unsigned hi = (unsigned)f2bf(v.z) | ((unsigned)f2bf(v.w) << 16);
    ((uint2*)out)[i] = make_uint2(lo, hi);
}

__global__ void cvt_all(const float* __restrict__ inp, const float* __restrict__ w_in,
                        const float* __restrict__ w_xp, const float* __restrict__ w_dt,
                        const float* __restrict__ w_out,
                        unsigned short* __restrict__ o_inp, unsigned short* __restrict__ o_win,
                        unsigned short* __restrict__ o_wxp, unsigned short* __restrict__ o_wdt,
                        unsigned short* __restrict__ o_wout)
{
    const long t = (long)blockIdx.x * 256 + threadIdx.x;
    const long gs = (long)gridDim.x * 256;
    for (long i = t; i < 8388608 / 4; i += gs) cvt4(inp, o_inp, i);
    for (long i = t; i < 4194304 / 4; i += gs) cvt4(w_in, o_win, i);
    for (long i = t; i < 2097152 / 4; i += gs) cvt4(w_out, o_wout, i);
    for (long i = t; i < 131072 / 4; i += gs) cvt4(w_dt, o_wdt, i);
    for (long i = t; i < 262144 / 4; i += gs) {
        const int r = (int)(i >> 9);
        if (r < 80) cvt4(w_xp, o_wxp, i);
        else ((uint2*)o_wxp)[i] = make_uint2(0u, 0u);
    }
}

// depthwise causal conv (K=4) + bias + silu; 2 channels per thread (u32 I/O).
__global__ void conv_silu_k(const unsigned short* __restrict__ xz,
                            const float* __restrict__ cw,
                            const float* __restrict__ cb,
                            unsigned short* __restrict__ xc)
{
    const int ep = blockIdx.y * 256 + threadIdx.x;
    const int e0 = ep * 2, e1 = e0 + 1;
    const int b = blockIdx.z;
    const int l0 = blockIdx.x * 32;
    const float wa0 = cw[e0 * 4], wa1 = cw[e0 * 4 + 1], wa2 = cw[e0 * 4 + 2], wa3 = cw[e0 * 4 + 3];
    const float wb0 = cw[e1 * 4], wb1 = cw[e1 * 4 + 1], wb2 = cw[e1 * 4 + 2], wb3 = cw[e1 * 4 + 3];
    const float ba = cb[e0], bb = cb[e1];
    const unsigned* xrow = (const unsigned*)(xz + (long)b * LL * 4096) + ep;
    unsigned* orow = (unsigned*)(xc + (long)b * LL * 2048) + ep;

    float a3 = 0.f, a2 = 0.f, a1 = 0.f, b3 = 0.f, b2 = 0.f, b1 = 0.f;
    if (l0 >= 3) { unsigned u = xrow[(long)(l0 - 3) * 2048]; a3 = bf2f(u & 0xffff); b3 = bf2f(u >> 16); }
    if (l0 >= 2) { unsigned u = xrow[(long)(l0 - 2) * 2048]; a2 = bf2f(u & 0xffff); b2 = bf2f(u >> 16); }
    if (l0 >= 1) { unsigned u = xrow[(long)(l0 - 1) * 2048]; a1 = bf2f(u & 0xffff); b1 = bf2f(u >> 16); }
    for (int l = l0; l < l0 + 32; ++l) {
        unsigned u = xrow[(long)l * 2048];
        float xa = bf2f(u & 0xffff), xb = bf2f(u >> 16);
        float va = ba + wa0 * a3 + wa1 * a2 + wa2 * a1 + wa3 * xa;
        float vb = bb + wb0 * b3 + wb1 * b2 + wb2 * b1 + wb3 * xb;
        float sa = va / (1.f + __expf(-va));
        float sb = vb / (1.f + __expf(-vb));
        orow[(long)l * 1024] = (unsigned)f2bf(sa) | ((unsigned)f2bf(sb) << 16);
        a3 = a2; a2 = a1; a1 = xa;
        b3 = b2; b2 = b1; b1 = xb;
    }
}

// ------- chunked parallel SSM scan, 2 channels/thread (NC=64, CH=32) -------
__global__ __launch_bounds__(256)
void scan_local(const unsigned short* __restrict__ delta,
                const unsigned short* __restrict__ xconv,
                const float* __restrict__ dbc,
                const float* __restrict__ A_log,
                float* __restrict__ hend, float* __restrict__ Ssum)
{
    const int ep = blockIdx.x * 256 + threadIdx.x;
    const int e0 = ep * 2;
    const int c = blockIdx.y, b = blockIdx.z;
    const int l0 = c * CH;
    float An[16];
#pragma unroll
    for (int n = 0; n < 16; ++n) An[n] = -__expf(A_log[e0 * 8 + n]);
    float h[16] = {};
    float S0 = 0.f, S1 = 0.f;
    const unsigned* drow = (const unsigned*)(delta + ((long)b * LL + l0) * EE) + ep;
    const unsigned* urow = (const unsigned*)(xconv + ((long)b * LL + l0) * EE) + ep;
    const float* bc = dbc + ((long)b * LL + l0) * 128;
    for (int l = 0; l < CH; ++l) {
        unsigned dv = drow[(long)l * 1024];
        unsigned uv = urow[(long)l * 1024];
        float d0 = bf2f(dv & 0xffff), d1 = bf2f(dv >> 16);
        float u0 = bf2f(uv & 0xffff), u1 = bf2f(uv >> 16);
        float du0 = d0 * u0, du1 = d1 * u1;
        S0 += d0; S1 += d1;
#pragma unroll
        for (int n = 0; n < 8; ++n) {
            float bn = bc[l * 128 + 64 + n];
            h[n]     = h[n]     * __expf(d0 * An[n])     + du0 * bn;
            h[8 + n] = h[8 + n] * __expf(d1 * An[8 + n]) + du1 * bn;
        }
    }
    const long o = ((long)b * NC + c) * EE + e0;
#pragma unroll
    for (int n = 0; n < 8; ++n) { hend[o * 8 + n] = h[n]; hend[(o + 1) * 8 + n] = h[8 + n]; }
    Ssum[o] = S0; Ssum[o + 1] = S1;
}

// combine parallelized over (b,e,n): 65536 threads = 256 blocks.
__global__ __launch_bounds__(256)
void scan_combine(const float* __restrict__ hend, const float* __restrict__ Ssum,
                  const float* __restrict__ A_log, float* __restrict__ hin)
{
    const int t = blockIdx.x * 256 + threadIdx.x;
    const int n = t & 7;
    const int be = t >> 3;
    const int b = be >> 11, e = be & 2047;
    const float An = -__expf(A_log[e * 8 + n]);
    float h = 0.f;
    for (int c = 0; c < NC; ++c) {
        const long o = ((long)b * NC + c) * EE + e;
        hin[o * 8 + n] = h;
        h = h * __expf(An * Ssum[o]) + hend[o * 8 + n];
    }
}

__global__ __launch_bounds__(256)
void scan_final(const unsigned short* __restrict__ delta,
                const unsigned short* __restrict__ xconv,
                const float* __restrict__ dbc,
                const unsigned short* __restrict__ xz,
                const float* __restrict__ A_log,
                const float* __restrict__ Dparam,
                const float* __restrict__ hin,
                unsigned short* __restrict__ yg)
{
    const int ep = blockIdx.x * 256 + threadIdx.x;
    const int e0 = ep * 2;
    const int c = blockIdx.y, b = blockIdx.z;
    const int l0 = c * CH;
    float An[16];
#pragma unroll
    for (int n = 0; n < 16; ++n) An[n] = -__expf(A_log[e0 * 8 + n]);
    const float Dp0 = Dparam[e0], Dp1 = Dparam[e0 + 1];
    float h[16];
    const long o = ((long)b * NC + c) * EE + e0;
#pragma unroll
    for (int n = 0; n < 8; ++n) { h[n] = hin[o * 8 + n]; h[8 + n] = hin[(o + 1) * 8 + n]; }
    const unsigned* drow = (const unsigned*)(delta + ((long)b * LL + l0) * EE) + ep;
    const unsigned* urow = (const unsigned*)(xconv + ((long)b * LL + l0) * EE) + ep;
    const unsigned* zrow = (const unsigned*)(xz + ((long)b * LL + l0) * 4096 + 2048) + ep;
    const float* bc = dbc + ((long)b * LL + l0) * 128;
    unsigned* yrow = (unsigned*)(yg + ((long)b * LL + l0) * EE) + ep;
    for (int l = 0; l < CH; ++l) {
        unsigned dv = drow[(long)l * 1024];
        unsigned uv = urow[(long)l * 1024];
        float d0 = bf2f(dv & 0xffff), d1 = bf2f(dv >> 16);
        float u0 = bf2f(uv & 0xffff), u1 = bf2f(uv >> 16);
        float du0 = d0 * u0, du1 = d1 * u1;
        float y0 = 0.f, y1 = 0.f;
#pragma unroll
        for (int n = 0; n < 8; ++n) {
            float bn = bc[l * 128 + 64 + n];
            float cn = bc[l * 128 + 72 + n];
            h[n]     = h[n]     * __expf(d0 * An[n])     + du0 * bn;
            h[8 + n] = h[8 + n] * __expf(d1 * An[8 + n]) + du1 * bn;
            y0 += h[n] * cn;
            y1 += h[8 + n] * cn;
        }
        y0 += u0 * Dp0; y1 += u1 * Dp1;
        unsigned zv = zrow[(long)l * 2048];
        float z0 = bf2f(zv & 0xffff), z1 = bf2f(zv >> 16);
        float g0 = z0 / (1.f + __expf(-z0));
        float g1 = z1 / (1.f + __expf(-z1));
        yrow[(long)l * 1024] = (unsigned)f2bf(y0 * g0) | ((unsigned)f2bf(y1 * g1) << 16);
    }
}

__global__ __launch_bounds__(256)
void rmsnorm_k(const unsigned short* __restrict__ in, const float* __restrict__ w,
               float* __restrict__ out)
{
    const int row = blockIdx.x;
    uint2 v2 = *(const uint2*)(in + (long)row * 1024 + threadIdx.x * 4);
    float x0 = bf2f(v2.x & 0xffff), x1 = bf2f(v2.x >> 16);
    float x2 = bf2f(v2.y & 0xffff), x3 = bf2f(v2.y >> 16);
    float ss = x0 * x0 + x1 * x1 + x2 * x2 + x3 * x3;
#pragma unroll
    for (int m = 32; m >= 1; m >>= 1) ss += __shfl_xor(ss, m, 64);
    __shared__ float wsum[4];
    const int wave = threadIdx.x >> 6;
    if ((threadIdx.x & 63) == 0) wsum[wave] = ss;
    __syncthreads();
    float tot = wsum[0] + wsum[1] + wsum[2] + wsum[3];
    float sc = rsqrtf(tot * (1.f / 1024.f) + 1e-5f);
    float4 wv = ((const float4*)w)[threadIdx.x];
    float4 o;
    o.x = x0 * sc * wv.x; o.y = x1 * sc * wv.y;
    o.z = x2 * sc * wv.z; o.w = x3 * sc * wv.w;
    ((float4*)(out + (long)row * 1024))[threadIdx.x] = o;
}

extern "C" void kernel_launch(void* const* d_in, const int* in_sizes, int n_in,
                              void* d_out, int out_size, void* d_ws, size_t ws_size,
                              hipStream_t stream)
{
    const float* inp   = (const float*)d_in[0];
    const float* w_in  = (const float*)d_in[1];
    const float* convw = (const float*)d_in[2];
    const float* convb = (const float*)d_in[3];
    const float* w_xp  = (const float*)d_in[4];
    const float* w_dt  = (const float*)d_in[5];
    const float* b_dt  = (const float*)d_in[6];
    const float* A_log = (const float*)d_in[7];
    const float* Dp    = (const float*)d_in[8];
    const float* w_out = (const float*)d_in[9];
    const float* rmsw  = (const float*)d_in[10];

    char* ws = (char*)d_ws;
    const size_t MB = 1024 * 1024;
    unsigned short* inp_bf   = (unsigned short*)(ws + 0);        // 16MB (dead after GEMM1)
    unsigned short* win_bf   = (unsigned short*)(ws + 16 * MB);  // 8MB  (dead after GEMM1)
    unsigned short* xz_bf    = (unsigned short*)(ws + 24 * MB);  // 64MB (live until scan_final)
    unsigned short* xconv_bf = (unsigned short*)(ws + 88 * MB);  // 32MB
    unsigned short* wxp_bf   = (unsigned short*)(ws + 120 * MB); // 0.5MB
    float*          dbc      = (float*)(ws + 121 * MB);          // 4MB
    unsigned short* dt_bf    = (unsigned short*)(ws + 125 * MB); // 1MB
    unsigned short* wdt_bf   = (unsigned short*)(ws + 126 * MB); // 0.25MB
    unsigned short* delta_bf = (unsigned short*)(ws + 127 * MB); // 32MB
    unsigned short* yg_bf    = (unsigned short*)(ws + 191 * MB); // 32MB
    unsigned short* wout_bf  = (unsigned short*)(ws + 223 * MB); // 4MB
    float*          dbc_part = (float*)(ws + 159 * MB);          // 16MB (xp partials)
    float*          hend     = (float*)(ws + 159 * MB);          // 16MB (after reduce)
    float*          hin      = (float*)(ws + 175 * MB);          // 16MB
    float*          Ssum     = (float*)(ws + 0);                 // 2MB  (over dead inp_bf)
    unsigned short* out_pre  = (unsigned short*)(ws + 0);        // 16MB bf16 (after scans)

    hipFuncSetAttribute((const void*)gemm8p<1, 256, 4>, hipFuncAttributeMaxDynamicSharedMemorySize, 131072);

    cvt_all<<<2048, 256, 0, stream>>>(inp, w_in, w_xp, w_dt, w_out,
                                      inp_bf, win_bf, wxp_bf, wdt_bf, wout_bf);

    // xz = inp @ in_proj_w^T (8192 x 4096, K=1024) -> bf16
    gemm8p<1, 256, 4><<<dim3(16, 32), 512, 131072, stream>>>(inp_bf, win_bf, xz_bf, 8192, 4096, 1024);
    // depthwise causal conv + silu
    conv_silu_k<<<dim3(64, 4, 4), 256, 0, stream>>>(xz_bf, convw, convb, xconv_bf);
    // dbc partials: xconv @ x_proj_w^T split-K (4 x 512)
    gemm_xp<<<dim3(64, 4), 256, 0, stream>>>(xconv_bf, wxp_bf, dbc_part);
    // reduce partials -> dbc f32 + dt bf16
    reduce_dbc<<<4096, 256, 0, stream>>>(dbc_part, dbc, dt_bf);
    // delta = softplus(dt @ dt_proj_w^T + b) -> bf16
    gemm_dt<<<dim3(16, 64), 256, 0, stream>>>(dt_bf, wdt_bf, b_dt, delta_bf);
    // chunked parallel SSM scan
    scan_local<<<dim3(4, NC, 4), 256, 0, stream>>>(delta_bf, xconv_bf, dbc, A_log, hend, Ssum);
    scan_combine<<<256, 256, 0, stream>>>(hend, Ssum, A_log, hin);
    scan_final<<<dim3(4, NC, 4), 256, 0, stream>>>(delta_bf, xconv_bf, dbc, xz_bf, A_log, Dp, hin, yg_bf);
    // out_pre = ygated @ out_proj_w^T (8192 x 1024, K=2048) -> bf16 (m97-style 128^2, 512 blocks)
    gemm128<<<dim3(8, 64), 256, 0, stream>>>(yg_bf, wout_bf, out_pre, 8192, 1024, 2048);
    // RMSNorm (bf16 in, f32 out)
    rmsnorm_k<<<8192, 256, 0, stream>>>(out_pre, rmsw, (float*)d_out);
}

// Round 10
// 321.677 us; speedup vs baseline: 1.0515x; 1.0515x over previous
//
#include <hip/hip_runtime.h>

#define LL 2048
#define EE 2048
#define DD 1024
#define NC 64    // chunks along L
#define CH 32    // chunk length (NC*CH == LL)

typedef short bf16x8 __attribute__((ext_vector_type(8)));
typedef float f32x4 __attribute__((ext_vector_type(4)));

__device__ inline float bf2f(unsigned short u) {
    union { unsigned u; float f; } v; v.u = ((unsigned)u) << 16; return v.f;
}
__device__ inline unsigned short f2bf(float f) {
    union { float f; unsigned u; } v; v.f = f;
    unsigned r = v.u + 0x7fff + ((v.u >> 16) & 1);
    return (unsigned short)(r >> 16);
}

__device__ inline void gload_lds16(const void* g, void* lds) {
    __builtin_amdgcn_global_load_lds(
        (const __attribute__((address_space(1))) unsigned int*)g,
        (__attribute__((address_space(3))) unsigned int*)lds, 16, 0, 0);
}

// ================= 256xBN 8-phase counted-vmcnt GEMM =================
template<int MODE, int BN, int STRIPE>
__global__ __launch_bounds__(512, 2)
void gemm8p(const unsigned short* __restrict__ A,
            const unsigned short* __restrict__ Bw,
            void* __restrict__ Cout,
            int M, int N, int K)
{
    constexpr int NREP = BN / 64;
    constexpr int RB   = BN / 128;
    constexpr int LH   = 2 + RB;
    constexpr int NSTRIP = BN / 4;

    extern __shared__ short lds[];
    short* Asm = lds;                    // [2buf][2kh][256][32]
    short* Bsm = lds + 2 * 2 * 256 * 32; // [2buf][2kh][BN][32]

    const int tid = threadIdx.x;
    const int w = tid >> 6, lane = tid & 63;
    const int wm = w >> 2, wn = w & 3;

    const int gx = N / BN;
    int lin = blockIdx.y * gx + blockIdx.x;
    const int k = lin & 7, loc = lin >> 3;
    const int bpc = STRIPE * gx;
    const int j = loc / bpc;
    const int wi = loc % bpc;
    const int my = (k + 8 * j) * STRIPE + wi / gx;
    const int nx = wi % gx;
    const long m0 = (long)my * 256;
    const long n0 = (long)nx * BN;

    const int g = (tid & 3) ^ ((tid >> 3) & 3);
    const int arow = tid >> 2;
    const unsigned short* Ag = A + (m0 + arow) * (long)K + g * 8;
    const unsigned short* Bg = Bw + (n0 + arow) * (long)K + g * 8;
    const int ldsrow = w * 16;

    auto stageA = [&](int buf, int kh, int jj, int kt) {
        gload_lds16(Ag + (long)jj * 128 * K + kt * 64 + kh * 32,
                    Asm + ((buf * 2 + kh) * 256 + jj * 128 + ldsrow) * 32);
    };
    auto stageB = [&](int buf, int kh, int jj, int kt) {
        gload_lds16(Bg + (long)jj * 128 * K + kt * 64 + kh * 32,
                    Bsm + ((buf * 2 + kh) * BN + jj * 128 + ldsrow) * 32);
    };

    f32x4 acc[8][NREP] = {};

    stageA(0, 0, 0, 0); stageA(0, 0, 1, 0);
#pragma unroll
    for (int jj = 0; jj < RB; ++jj) stageB(0, 0, jj, 0);
    stageA(0, 1, 0, 0); stageA(0, 1, 1, 0);
#pragma unroll
    for (int jj = 0; jj < RB; ++jj) stageB(0, 1, jj, 0);

    const int NT = K / 64;
    const int rr = lane & 15;
    const int sl = ((lane >> 4) ^ ((rr >> 1) & 3)) * 8;

    for (int t = 0; t < NT; ++t) {
        const int cur = t & 1, nxt = cur ^ 1;
        const bool more = (t + 1 < NT);

        asm volatile("s_waitcnt vmcnt(%0)" :: "i"(LH) : "memory");
        __builtin_amdgcn_s_barrier();

        const short* Ac0 = Asm + (cur * 2 + 0) * 256 * 32;
        const short* Bc0 = Bsm + (cur * 2 + 0) * BN * 32;
        if (more) { stageA(nxt, 0, 0, t + 1); stageA(nxt, 0, 1, t + 1); }
        bf16x8 a[4], b[NREP];
#pragma unroll
        for (int m = 0; m < 4; ++m)
            a[m] = *(const bf16x8*)&Ac0[(wm * 128 + m * 16 + rr) * 32 + sl];
#pragma unroll
        for (int n = 0; n < NREP; ++n)
            b[n] = *(const bf16x8*)&Bc0[(wn * NSTRIP + n * 16 + rr) * 32 + sl];
        __builtin_amdgcn_s_setprio(1);
#pragma unroll
        for (int m = 0; m < 4; ++m)
#pragma unroll
            for (int n = 0; n < NREP; ++n)
                acc[m][n] = __builtin_amdgcn_mfma_f32_16x16x32_bf16(a[m], b[n], acc[m][n], 0, 0, 0);
        __builtin_amdgcn_s_setprio(0);
        if (more) {
#pragma unroll
            for (int jj = 0; jj < RB; ++jj) stageB(nxt, 0, jj, t + 1);
        }
#pragma unroll
        for (int m = 0; m < 4; ++m)
            a[m] = *(const bf16x8*)&Ac0[(wm * 128 + 64 + m * 16 + rr) * 32 + sl];
        __builtin_amdgcn_s_setprio(1);
#pragma unroll
        for (int m = 0; m < 4; ++m)
#pragma unroll
            for (int n = 0; n < NREP; ++n)
                acc[4 + m][n] = __builtin_amdgcn_mfma_f32_16x16x32_bf16(a[m], b[n], acc[4 + m][n], 0, 0, 0);
        __builtin_amdgcn_s_setprio(0);

        if (more) { asm volatile("s_waitcnt vmcnt(%0)" :: "i"(LH) : "memory"); }
        else      { asm volatile("s_waitcnt vmcnt(0)" ::: "memory"); }
        __builtin_amdgcn_s_barrier();

        const short* Ac1 = Asm + (cur * 2 + 1) * 256 * 32;
        const short* Bc1 = Bsm + (cur * 2 + 1) * BN * 32;
        if (more) { stageA(nxt, 1, 0, t + 1); stageA(nxt, 1, 1, t + 1); }
#pragma unroll
        for (int m = 0; m < 4; ++m)
            a[m] = *(const bf16x8*)&Ac1[(wm * 128 + m * 16 + rr) * 32 + sl];
#pragma unroll
        for (int n = 0; n < NREP; ++n)
            b[n] = *(const bf16x8*)&Bc1[(wn * NSTRIP + n * 16 + rr) * 32 + sl];
        __builtin_amdgcn_s_setprio(1);
#pragma unroll
        for (int m = 0; m < 4; ++m)
#pragma unroll
            for (int n = 0; n < NREP; ++n)
                acc[m][n] = __builtin_amdgcn_mfma_f32_16x16x32_bf16(a[m], b[n], acc[m][n], 0, 0, 0);
        __builtin_amdgcn_s_setprio(0);
        if (more) {
#pragma unroll
            for (int jj = 0; jj < RB; ++jj) stageB(nxt, 1, jj, t + 1);
        }
#pragma unroll
        for (int m = 0; m < 4; ++m)
            a[m] = *(const bf16x8*)&Ac1[(wm * 128 + 64 + m * 16 + rr) * 32 + sl];
        __builtin_amdgcn_s_setprio(1);
#pragma unroll
        for (int m = 0; m < 4; ++m)
#pragma unroll
            for (int n = 0; n < NREP; ++n)
                acc[4 + m][n] = __builtin_amdgcn_mfma_f32_16x16x32_bf16(a[m], b[n], acc[4 + m][n], 0, 0, 0);
        __builtin_amdgcn_s_setprio(0);
    }

#pragma unroll
    for (int m = 0; m < 8; ++m) {
#pragma unroll
        for (int n = 0; n < NREP; ++n) {
#pragma unroll
            for (int r = 0; r < 4; ++r) {
                long row = m0 + wm * 128 + m * 16 + (lane >> 4) * 4 + r;
                long col = n0 + wn * NSTRIP + n * 16 + (lane & 15);
                float v = acc[m][n][r];
                if (MODE == 0) ((float*)Cout)[row * N + col] = v;
                else           ((unsigned short*)Cout)[row * N + col] = f2bf(v);
            }
        }
    }
}

// ============ x_proj split-K GEMM: 128x128 tile, K-slice 512, kz 0..3 ============
__global__ __launch_bounds__(256)
void gemm_xp(const unsigned short* __restrict__ A,
             const unsigned short* __restrict__ Bw,
             float* __restrict__ Cout)
{
    __shared__ short As[128 * 32];
    __shared__ short Bs[128 * 32];
    const int tid = threadIdx.x;
    const int wave = tid >> 6, lane = tid & 63;
    const int wm = wave >> 1, wn = wave & 1;
    const long m0 = (long)blockIdx.x * 128;
    const int kz = blockIdx.y;
    float* out = Cout + (long)kz * 8192 * 128;

    f32x4 acc[4][4] = {};

    const int srow = lane >> 2;
    const int g = (lane & 3) ^ ((srow >> 1) & 3);
    const int c0 = wave, c1 = wave + 4;

    for (int k0 = kz * 512; k0 < kz * 512 + 512; k0 += 32) {
        gload_lds16(A + (m0 + c0 * 16 + srow) * 2048L + k0 + g * 8, &As[c0 * 16 * 32]);
        gload_lds16(A + (m0 + c1 * 16 + srow) * 2048L + k0 + g * 8, &As[c1 * 16 * 32]);
        gload_lds16(Bw + (c0 * 16 + srow) * 2048L + k0 + g * 8, &Bs[c0 * 16 * 32]);
        gload_lds16(Bw + (c1 * 16 + srow) * 2048L + k0 + g * 8, &Bs[c1 * 16 * 32]);
        __syncthreads();

        const int rr = lane & 15;
        const int sl = ((lane >> 4) ^ ((rr >> 1) & 3)) * 8;
        bf16x8 af[4], bfr[4];
#pragma unroll
        for (int m = 0; m < 4; ++m)
            af[m] = *(const bf16x8*)&As[(wm * 64 + m * 16 + rr) * 32 + sl];
#pragma unroll
        for (int n = 0; n < 4; ++n)
            bfr[n] = *(const bf16x8*)&Bs[(wn * 64 + n * 16 + rr) * 32 + sl];
#pragma unroll
        for (int m = 0; m < 4; ++m)
#pragma unroll
            for (int n = 0; n < 4; ++n)
                acc[m][n] = __builtin_amdgcn_mfma_f32_16x16x32_bf16(af[m], bfr[n], acc[m][n], 0, 0, 0);
        __syncthreads();
    }

#pragma unroll
    for (int m = 0; m < 4; ++m)
#pragma unroll
        for (int n = 0; n < 4; ++n)
#pragma unroll
            for (int r = 0; r < 4; ++r) {
                long row = m0 + wm * 64 + m * 16 + (lane >> 4) * 4 + r;
                long col = wn * 64 + n * 16 + (lane & 15);
                out[row * 128 + col] = acc[m][n][r];
            }
}

// sum 4 K-partials -> dbc f32; cols < 64 also -> dt bf16
__global__ void reduce_dbc(const float* __restrict__ part,
                           float* __restrict__ dbc,
                           unsigned short* __restrict__ dt)
{
    const long i = (long)blockIdx.x * 256 + threadIdx.x;
    float s = part[i] + part[i + 1048576] + part[i + 2 * 1048576] + part[i + 3 * 1048576];
    dbc[i] = s;
    const int c = (int)(i & 127);
    if (c < 64) dt[(i >> 7) * 64 + c] = f2bf(s);
}

// ===== dt_proj: light 128x128 2-phase GEMM, K=64 =====
__global__ __launch_bounds__(256)
void gemm_dt(const unsigned short* __restrict__ A,
             const unsigned short* __restrict__ Bw,
             const float* __restrict__ bias,
             unsigned short* __restrict__ Cout)
{
    __shared__ short As[128 * 32];
    __shared__ short Bs[128 * 32];
    const int tid = threadIdx.x;
    const int wave = tid >> 6, lane = tid & 63;
    const int wm = wave >> 1, wn = wave & 1;
    const long m0 = (long)blockIdx.y * 128;
    const long n0 = (long)blockIdx.x * 128;

    f32x4 acc[4][4] = {};

    const int srow = lane >> 2;
    const int g = (lane & 3) ^ ((srow >> 1) & 3);
    const int c0 = wave, c1 = wave + 4;

    for (int k0 = 0; k0 < 64; k0 += 32) {
        gload_lds16(A + (m0 + c0 * 16 + srow) * 64L + k0 + g * 8, &As[c0 * 16 * 32]);
        gload_lds16(A + (m0 + c1 * 16 + srow) * 64L + k0 + g * 8, &As[c1 * 16 * 32]);
        gload_lds16(Bw + (n0 + c0 * 16 + srow) * 64L + k0 + g * 8, &Bs[c0 * 16 * 32]);
        gload_lds16(Bw + (n0 + c1 * 16 + srow) * 64L + k0 + g * 8, &Bs[c1 * 16 * 32]);
        __syncthreads();

        const int rr = lane & 15;
        const int sl = ((lane >> 4) ^ ((rr >> 1) & 3)) * 8;
        bf16x8 af[4], bfr[4];
#pragma unroll
        for (int m = 0; m < 4; ++m)
            af[m] = *(const bf16x8*)&As[(wm * 64 + m * 16 + rr) * 32 + sl];
#pragma unroll
        for (int n = 0; n < 4; ++n)
            bfr[n] = *(const bf16x8*)&Bs[(wn * 64 + n * 16 + rr) * 32 + sl];
#pragma unroll
        for (int m = 0; m < 4; ++m)
#pragma unroll
            for (int n = 0; n < 4; ++n)
                acc[m][n] = __builtin_amdgcn_mfma_f32_16x16x32_bf16(af[m], bfr[n], acc[m][n], 0, 0, 0);
        __syncthreads();
    }

#pragma unroll
    for (int m = 0; m < 4; ++m)
#pragma unroll
        for (int n = 0; n < 4; ++n)
#pragma unroll
            for (int r = 0; r < 4; ++r) {
                long row = m0 + wm * 64 + m * 16 + (lane >> 4) * 4 + r;
                long col = n0 + wn * 64 + n * 16 + (lane & 15);
                float v = acc[m][n][r] + bias[col];
                float sp = (v > 20.f) ? v : log1pf(__expf(v));
                Cout[row * 2048 + col] = f2bf(sp);
            }
}

// ---- all f32->bf16 operand conversions in ONE launch ----
__device__ inline void cvt4(const float* __restrict__ in, unsigned short* __restrict__ out, long i) {
    float4 v = ((const float4*)in)[i];
    unsigned lo = (unsigned)f2bf(v.x) | ((unsigned)f2bf(v.y) << 16);
    unsigned hi = (unsigned)f2bf(v.z) | ((unsigned)f2bf(v.w) << 16);
    ((uint2*)out)[i] = make_uint2(lo, hi);
}

__global__ void cvt_all(const float* __restrict__ inp, const float* __restrict__ w_in,
                        const float* __restrict__ w_xp, const float* __restrict__ w_dt,
                        const float* __restrict__ w_out,
                        unsigned short* __restrict__ o_inp, unsigned short* __restrict__ o_win,
                        unsigned short* __restrict__ o_wxp, unsigned short* __restrict__ o_wdt,
                        unsigned short* __restrict__ o_wout)
{
    const long t = (long)blockIdx.x * 256 + threadIdx.x;
    const long gs = (long)gridDim.x * 256;
    for (long i = t; i < 8388608 / 4; i += gs) cvt4(inp, o_inp, i);
    for (long i = t; i < 4194304 / 4; i += gs) cvt4(w_in, o_win, i);
    for (long i = t; i < 2097152 / 4; i += gs) cvt4(w_out, o_wout, i);
    for (long i = t; i < 131072 / 4; i += gs) cvt4(w_dt, o_wdt, i);
    for (long i = t; i < 262144 / 4; i += gs) {
        const int r = (int)(i >> 9);
        if (r < 80) cvt4(w_xp, o_wxp, i);
        else ((uint2*)o_wxp)[i] = make_uint2(0u, 0u);
    }
}

// depthwise causal conv (K=4) + bias + silu; 4 channels per thread (uint2 I/O).
__global__ void conv_silu_k(const unsigned short* __restrict__ xz,
                            const float* __restrict__ cw,
                            const float* __restrict__ cb,
                            unsigned short* __restrict__ xc)
{
    const int eq = blockIdx.y * 256 + threadIdx.x;   // 0..511 channel quads
    const int e0 = eq * 4;
    const int b = blockIdx.z;
    const int l0 = blockIdx.x * 32;
    float w0[4], w1[4], w2[4], w3[4], bi[4];
#pragma unroll
    for (int c = 0; c < 4; ++c) {
        w0[c] = cw[(e0 + c) * 4 + 0]; w1[c] = cw[(e0 + c) * 4 + 1];
        w2[c] = cw[(e0 + c) * 4 + 2]; w3[c] = cw[(e0 + c) * 4 + 3];
        bi[c] = cb[e0 + c];
    }
    const uint2* xrow = (const uint2*)(xz + (long)b * LL * 4096) + eq;  // l-stride 1024 uint2
    uint2* orow = (uint2*)(xc + (long)b * LL * 2048) + eq;              // l-stride 512 uint2

    float s3[4] = {}, s2[4] = {}, s1[4] = {};
    auto unpack = [](uint2 u, float* f) {
        f[0] = bf2f(u.x & 0xffff); f[1] = bf2f(u.x >> 16);
        f[2] = bf2f(u.y & 0xffff); f[3] = bf2f(u.y >> 16);
    };
    if (l0 >= 3) { float f[4]; unpack(xrow[(long)(l0 - 3) * 1024], f);
#pragma unroll
        for (int c = 0; c < 4; ++c) s3[c] = f[c]; }
    if (l0 >= 2) { float f[4]; unpack(xrow[(long)(l0 - 2) * 1024], f);
#pragma unroll
        for (int c = 0; c < 4; ++c) s2[c] = f[c]; }
    if (l0 >= 1) { float f[4]; unpack(xrow[(long)(l0 - 1) * 1024], f);
#pragma unroll
        for (int c = 0; c < 4; ++c) s1[c] = f[c]; }
#pragma unroll 2
    for (int l = l0; l < l0 + 32; ++l) {
        float x[4]; unpack(xrow[(long)l * 1024], x);
        unsigned short o[4];
#pragma unroll
        for (int c = 0; c < 4; ++c) {
            float v = bi[c] + w0[c] * s3[c] + w1[c] * s2[c] + w2[c] * s1[c] + w3[c] * x[c];
            float s = v / (1.f + __expf(-v));
            o[c] = f2bf(s);
            s3[c] = s2[c]; s2[c] = s1[c]; s1[c] = x[c];
        }
        uint2 ov;
        ov.x = (unsigned)o[0] | ((unsigned)o[1] << 16);
        ov.y = (unsigned)o[2] | ((unsigned)o[3] << 16);
        orow[(long)l * 512] = ov;
    }
}

// ------- chunked parallel SSM scan, 2 channels/thread (NC=64, CH=32) -------
__global__ __launch_bounds__(256)
void scan_local(const unsigned short* __restrict__ delta,
                const unsigned short* __restrict__ xconv,
                const float* __restrict__ dbc,
                const float* __restrict__ A_log,
                float* __restrict__ hend, float* __restrict__ Ssum)
{
    const int ep = blockIdx.x * 256 + threadIdx.x;
    const int e0 = ep * 2;
    const int c = blockIdx.y, b = blockIdx.z;
    const int l0 = c * CH;
    float An[16];
#pragma unroll
    for (int n = 0; n < 16; ++n) An[n] = -__expf(A_log[e0 * 8 + n]);
    float h[16] = {};
    float S0 = 0.f, S1 = 0.f;
    const unsigned* drow = (const unsigned*)(delta + ((long)b * LL + l0) * EE) + ep;
    const unsigned* urow = (const unsigned*)(xconv + ((long)b * LL + l0) * EE) + ep;
    const float* bc = dbc + ((long)b * LL + l0) * 128;
#pragma unroll 2
    for (int l = 0; l < CH; ++l) {
        unsigned dv = drow[(long)l * 1024];
        unsigned uv = urow[(long)l * 1024];
        float d0 = bf2f(dv & 0xffff), d1 = bf2f(dv >> 16);
        float u0 = bf2f(uv & 0xffff), u1 = bf2f(uv >> 16);
        float du0 = d0 * u0, du1 = d1 * u1;
        S0 += d0; S1 += d1;
#pragma unroll
        for (int n = 0; n < 8; ++n) {
            float bn = bc[l * 128 + 64 + n];
            h[n]     = h[n]     * __expf(d0 * An[n])     + du0 * bn;
            h[8 + n] = h[8 + n] * __expf(d1 * An[8 + n]) + du1 * bn;
        }
    }
    const long o = ((long)b * NC + c) * EE + e0;
#pragma unroll
    for (int n = 0; n < 8; ++n) { hend[o * 8 + n] = h[n]; hend[(o + 1) * 8 + n] = h[8 + n]; }
    Ssum[o] = S0; Ssum[o + 1] = S1;
}

// combine parallelized over (b,e,n): 65536 threads = 256 blocks.
__global__ __launch_bounds__(256)
void scan_combine(const float* __restrict__ hend, const float* __restrict__ Ssum,
                  const float* __restrict__ A_log, float* __restrict__ hin)
{
    const int t = blockIdx.x * 256 + threadIdx.x;
    const int n = t & 7;
    const int be = t >> 3;
    const int b = be >> 11, e = be & 2047;
    const float An = -__expf(A_log[e * 8 + n]);
    float h = 0.f;
    for (int c = 0; c < NC; ++c) {
        const long o = ((long)b * NC + c) * EE + e;
        hin[o * 8 + n] = h;
        h = h * __expf(An * Ssum[o]) + hend[o * 8 + n];
    }
}

__global__ __launch_bounds__(256)
void scan_final(const unsigned short* __restrict__ delta,
                const unsigned short* __restrict__ xconv,
                const float* __restrict__ dbc,
                const unsigned short* __restrict__ xz,
                const float* __restrict__ A_log,
                const float* __restrict__ Dparam,
                const float* __restrict__ hin,
                unsigned short* __restrict__ yg)
{
    const int ep = blockIdx.x * 256 + threadIdx.x;
    const int e0 = ep * 2;
    const int c = blockIdx.y, b = blockIdx.z;
    const int l0 = c * CH;
    float An[16];
#pragma unroll
    for (int n = 0; n < 16; ++n) An[n] = -__expf(A_log[e0 * 8 + n]);
    const float Dp0 = Dparam[e0], Dp1 = Dparam[e0 + 1];
    float h[16];
    const long o = ((long)b * NC + c) * EE + e0;
#pragma unroll
    for (int n = 0; n < 8; ++n) { h[n] = hin[o * 8 + n]; h[8 + n] = hin[(o + 1) * 8 + n]; }
    const unsigned* drow = (const unsigned*)(delta + ((long)b * LL + l0) * EE) + ep;
    const unsigned* urow = (const unsigned*)(xconv + ((long)b * LL + l0) * EE) + ep;
    const unsigned* zrow = (const unsigned*)(xz + ((long)b * LL + l0) * 4096 + 2048) + ep;
    const float* bc = dbc + ((long)b * LL + l0) * 128;
    unsigned* yrow = (unsigned*)(yg + ((long)b * LL + l0) * EE) + ep;
#pragma unroll 2
    for (int l = 0; l < CH; ++l) {
        unsigned dv = drow[(long)l * 1024];
        unsigned uv = urow[(long)l * 1024];
        float d0 = bf2f(dv & 0xffff), d1 = bf2f(dv >> 16);
        float u0 = bf2f(uv & 0xffff), u1 = bf2f(uv >> 16);
        float du0 = d0 * u0, du1 = d1 * u1;
        float y0 = 0.f, y1 = 0.f;
#pragma unroll
        for (int n = 0; n < 8; ++n) {
            float bn = bc[l * 128 + 64 + n];
            float cn = bc[l * 128 + 72 + n];
            h[n]     = h[n]     * __expf(d0 * An[n])     + du0 * bn;
            h[8 + n] = h[8 + n] * __expf(d1 * An[8 + n]) + du1 * bn;
            y0 += h[n] * cn;
            y1 += h[8 + n] * cn;
        }
        y0 += u0 * Dp0; y1 += u1 * Dp1;
        unsigned zv = zrow[(long)l * 2048];
        float z0 = bf2f(zv & 0xffff), z1 = bf2f(zv >> 16);
        float g0 = z0 / (1.f + __expf(-z0));
        float g1 = z1 / (1.f + __expf(-z1));
        yrow[(long)l * 1024] = (unsigned)f2bf(y0 * g0) | ((unsigned)f2bf(y1 * g1) << 16);
    }
}

// RMSNorm: one wave per row, no LDS/barrier. grid 2048 x 256.
__global__ __launch_bounds__(256)
void rmsnorm_k(const unsigned short* __restrict__ in, const float* __restrict__ w,
               float* __restrict__ out)
{
    const int wave = threadIdx.x >> 6, lane = threadIdx.x & 63;
    const long row = (long)blockIdx.x * 4 + wave;
    const uint4* p = (const uint4*)(in + row * 1024) + lane * 2;
    uint4 a = p[0], bq = p[1];
    float x[16];
    x[0] = bf2f(a.x & 0xffff);  x[1] = bf2f(a.x >> 16);
    x[2] = bf2f(a.y & 0xffff);  x[3] = bf2f(a.y >> 16);
    x[4] = bf2f(a.z & 0xffff);  x[5] = bf2f(a.z >> 16);
    x[6] = bf2f(a.w & 0xffff);  x[7] = bf2f(a.w >> 16);
    x[8] = bf2f(bq.x & 0xffff); x[9] = bf2f(bq.x >> 16);
    x[10] = bf2f(bq.y & 0xffff); x[11] = bf2f(bq.y >> 16);
    x[12] = bf2f(bq.z & 0xffff); x[13] = bf2f(bq.z >> 16);
    x[14] = bf2f(bq.w & 0xffff); x[15] = bf2f(bq.w >> 16);
    float ss = 0.f;
#pragma unroll
    for (int i = 0; i < 16; ++i) ss += x[i] * x[i];
#pragma unroll
    for (int m = 32; m >= 1; m >>= 1) ss += __shfl_xor(ss, m, 64);
    const float sc = rsqrtf(ss * (1.f / 1024.f) + 1e-5f);
    const float4* wv = (const float4*)w + lane * 4;
    float* op = out + row * 1024 + lane * 16;
#pragma unroll
    for (int q = 0; q < 4; ++q) {
        float4 ww = wv[q];
        float4 o;
        o.x = x[q * 4 + 0] * sc * ww.x;
        o.y = x[q * 4 + 1] * sc * ww.y;
        o.z = x[q * 4 + 2] * sc * ww.z;
        o.w = x[q * 4 + 3] * sc * ww.w;
        ((float4*)op)[q] = o;
    }
}

extern "C" void kernel_launch(void* const* d_in, const int* in_sizes, int n_in,
                              void* d_out, int out_size, void* d_ws, size_t ws_size,
                              hipStream_t stream)
{
    const float* inp   = (const float*)d_in[0];
    const float* w_in  = (const float*)d_in[1];
    const float* convw = (const float*)d_in[2];
    const float* convb = (const float*)d_in[3];
    const float* w_xp  = (const float*)d_in[4];
    const float* w_dt  = (const float*)d_in[5];
    const float* b_dt  = (const float*)d_in[6];
    const float* A_log = (const float*)d_in[7];
    const float* Dp    = (const float*)d_in[8];
    const float* w_out = (const float*)d_in[9];
    const float* rmsw  = (const float*)d_in[10];

    char* ws = (char*)d_ws;
    const size_t MB = 1024 * 1024;
    unsigned short* inp_bf   = (unsigned short*)(ws + 0);        // 16MB (dead after GEMM1)
    unsigned short* win_bf   = (unsigned short*)(ws + 16 * MB);  // 8MB  (dead after GEMM1)
    unsigned short* xz_bf    = (unsigned short*)(ws + 24 * MB);  // 64MB (live until scan_final)
    unsigned short* xconv_bf = (unsigned short*)(ws + 88 * MB);  // 32MB
    unsigned short* wxp_bf   = (unsigned short*)(ws + 120 * MB); // 0.5MB
    float*          dbc      = (float*)(ws + 121 * MB);          // 4MB
    unsigned short* dt_bf    = (unsigned short*)(ws + 125 * MB); // 1MB
    unsigned short* wdt_bf   = (unsigned short*)(ws + 126 * MB); // 0.25MB
    unsigned short* delta_bf = (unsigned short*)(ws + 127 * MB); // 32MB
    unsigned short* yg_bf    = (unsigned short*)(ws + 191 * MB); // 32MB
    unsigned short* wout_bf  = (unsigned short*)(ws + 223 * MB); // 4MB
    float*          dbc_part = (float*)(ws + 159 * MB);          // 16MB (xp partials)
    float*          hend     = (float*)(ws + 159 * MB);          // 16MB (after reduce)
    float*          hin      = (float*)(ws + 175 * MB);          // 16MB
    float*          Ssum     = (float*)(ws + 0);                 // 2MB  (over dead inp_bf)
    unsigned short* out_pre  = (unsigned short*)(ws + 0);        // 16MB bf16 (after scans)

    hipFuncSetAttribute((const void*)gemm8p<1, 256, 4>, hipFuncAttributeMaxDynamicSharedMemorySize, 131072);
    hipFuncSetAttribute((const void*)gemm8p<1, 128, 2>, hipFuncAttributeMaxDynamicSharedMemorySize, 98304);

    cvt_all<<<2048, 256, 0, stream>>>(inp, w_in, w_xp, w_dt, w_out,
                                      inp_bf, win_bf, wxp_bf, wdt_bf, wout_bf);

    // xz = inp @ in_proj_w^T (8192 x 4096, K=1024) -> bf16
    gemm8p<1, 256, 4><<<dim3(16, 32), 512, 131072, stream>>>(inp_bf, win_bf, xz_bf, 8192, 4096, 1024);
    // depthwise causal conv + silu (4 channels/thread)
    conv_silu_k<<<dim3(64, 2, 4), 256, 0, stream>>>(xz_bf, convw, convb, xconv_bf);
    // dbc partials: xconv @ x_proj_w^T split-K (4 x 512)
    gemm_xp<<<dim3(64, 4), 256, 0, stream>>>(xconv_bf, wxp_bf, dbc_part);
    // reduce partials -> dbc f32 + dt bf16
    reduce_dbc<<<4096, 256, 0, stream>>>(dbc_part, dbc, dt_bf);
    // delta = softplus(dt @ dt_proj_w^T + b) -> bf16
    gemm_dt<<<dim3(16, 64), 256, 0, stream>>>(dt_bf, wdt_bf, b_dt, delta_bf);
    // chunked parallel SSM scan
    scan_local<<<dim3(4, NC, 4), 256, 0, stream>>>(delta_bf, xconv_bf, dbc, A_log, hend, Ssum);
    scan_combine<<<256, 256, 0, stream>>>(hend, Ssum, A_log, hin);
    scan_final<<<dim3(4, NC, 4), 256, 0, stream>>>(delta_bf, xconv_bf, dbc, xz_bf, A_log, Dp, hin, yg_bf);
    // out_pre = ygated @ out_proj_w^T (8192 x 1024, K=2048) -> bf16
    gemm8p<1, 128, 2><<<dim3(8, 32), 512, 98304, stream>>>(yg_bf, wout_bf, out_pre, 8192, 1024, 2048);
    // RMSNorm (bf16 in, f32 out), one wave per row
    rmsnorm_k<<<2048, 256, 0, stream>>>(out_pre, rmsw, (float*)d_out);
}

// Round 11
// 320.101 us; speedup vs baseline: 1.0567x; 1.0049x over previous
//
#include <hip/hip_runtime.h>

#define LL 2048
#define EE 2048
#define DD 1024
#define NC 64    // chunks along L
#define CH 32    // chunk length (NC*CH == LL)

typedef short bf16x8 __attribute__((ext_vector_type(8)));
typedef float f32x4 __attribute__((ext_vector_type(4)));

__device__ inline float bf2f(unsigned short u) {
    union { unsigned u; float f; } v; v.u = ((unsigned)u) << 16; return v.f;
}
__device__ inline unsigned short f2bf(float f) {
    union { float f; unsigned u; } v; v.f = f;
    unsigned r = v.u + 0x7fff + ((v.u >> 16) & 1);
    return (unsigned short)(r >> 16);
}

__device__ inline void gload_lds16(const void* g, void* lds) {
    __builtin_amdgcn_global_load_lds(
        (const __attribute__((address_space(1))) unsigned int*)g,
        (__attribute__((address_space(3))) unsigned int*)lds, 16, 0, 0);
}

// ================= 256xBN 8-phase counted-vmcnt GEMM =================
// SPLITK>1: blockIdx.z picks K-slice; bf16 partial written at Cout + z*M*N.
template<int MODE, int BN, int STRIPE, int SPLITK>
__global__ __launch_bounds__(512, 2)
void gemm8p(const unsigned short* __restrict__ A,
            const unsigned short* __restrict__ Bw,
            void* __restrict__ Cout,
            int M, int N, int K)
{
    constexpr int NREP = BN / 64;
    constexpr int RB   = BN / 128;
    constexpr int LH   = 2 + RB;
    constexpr int NSTRIP = BN / 4;

    extern __shared__ short lds[];
    short* Asm = lds;                    // [2buf][2kh][256][32]
    short* Bsm = lds + 2 * 2 * 256 * 32; // [2buf][2kh][BN][32]

    const int tid = threadIdx.x;
    const int w = tid >> 6, lane = tid & 63;
    const int wm = w >> 2, wn = w & 3;

    const int gx = N / BN;
    int lin = blockIdx.y * gx + blockIdx.x;
    const int k = lin & 7, loc = lin >> 3;
    const int bpc = STRIPE * gx;
    const int j = loc / bpc;
    const int wi = loc % bpc;
    const int my = (k + 8 * j) * STRIPE + wi / gx;
    const int nx = wi % gx;
    const long m0 = (long)my * 256;
    const long n0 = (long)nx * BN;

    const int K2 = K / SPLITK;
    const int koff = (SPLITK > 1) ? (int)blockIdx.z * K2 : 0;

    const int g = (tid & 3) ^ ((tid >> 3) & 3);
    const int arow = tid >> 2;
    const unsigned short* Ag = A + (m0 + arow) * (long)K + koff + g * 8;
    const unsigned short* Bg = Bw + (n0 + arow) * (long)K + koff + g * 8;
    const int ldsrow = w * 16;

    auto stageA = [&](int buf, int kh, int jj, int kt) {
        gload_lds16(Ag + (long)jj * 128 * K + kt * 64 + kh * 32,
                    Asm + ((buf * 2 + kh) * 256 + jj * 128 + ldsrow) * 32);
    };
    auto stageB = [&](int buf, int kh, int jj, int kt) {
        gload_lds16(Bg + (long)jj * 128 * K + kt * 64 + kh * 32,
                    Bsm + ((buf * 2 + kh) * BN + jj * 128 + ldsrow) * 32);
    };

    f32x4 acc[8][NREP] = {};

    stageA(0, 0, 0, 0); stageA(0, 0, 1, 0);
#pragma unroll
    for (int jj = 0; jj < RB; ++jj) stageB(0, 0, jj, 0);
    stageA(0, 1, 0, 0); stageA(0, 1, 1, 0);
#pragma unroll
    for (int jj = 0; jj < RB; ++jj) stageB(0, 1, jj, 0);

    const int NT = K2 / 64;
    const int rr = lane & 15;
    const int sl = ((lane >> 4) ^ ((rr >> 1) & 3)) * 8;

    for (int t = 0; t < NT; ++t) {
        const int cur = t & 1, nxt = cur ^ 1;
        const bool more = (t + 1 < NT);

        asm volatile("s_waitcnt vmcnt(%0)" :: "i"(LH) : "memory");
        __builtin_amdgcn_s_barrier();

        const short* Ac0 = Asm + (cur * 2 + 0) * 256 * 32;
        const short* Bc0 = Bsm + (cur * 2 + 0) * BN * 32;
        if (more) { stageA(nxt, 0, 0, t + 1); stageA(nxt, 0, 1, t + 1); }
        bf16x8 a[4], b[NREP];
#pragma unroll
        for (int m = 0; m < 4; ++m)
            a[m] = *(const bf16x8*)&Ac0[(wm * 128 + m * 16 + rr) * 32 + sl];
#pragma unroll
        for (int n = 0; n < NREP; ++n)
            b[n] = *(const bf16x8*)&Bc0[(wn * NSTRIP + n * 16 + rr) * 32 + sl];
        __builtin_amdgcn_s_setprio(1);
#pragma unroll
        for (int m = 0; m < 4; ++m)
#pragma unroll
            for (int n = 0; n < NREP; ++n)
                acc[m][n] = __builtin_amdgcn_mfma_f32_16x16x32_bf16(a[m], b[n], acc[m][n], 0, 0, 0);
        __builtin_amdgcn_s_setprio(0);
        if (more) {
#pragma unroll
            for (int jj = 0; jj < RB; ++jj) stageB(nxt, 0, jj, t + 1);
        }
#pragma unroll
        for (int m = 0; m < 4; ++m)
            a[m] = *(const bf16x8*)&Ac0[(wm * 128 + 64 + m * 16 + rr) * 32 + sl];
        __builtin_amdgcn_s_setprio(1);
#pragma unroll
        for (int m = 0; m < 4; ++m)
#pragma unroll
            for (int n = 0; n < NREP; ++n)
                acc[4 + m][n] = __builtin_amdgcn_mfma_f32_16x16x32_bf16(a[m], b[n], acc[4 + m][n], 0, 0, 0);
        __builtin_amdgcn_s_setprio(0);

        if (more) { asm volatile("s_waitcnt vmcnt(%0)" :: "i"(LH) : "memory"); }
        else      { asm volatile("s_waitcnt vmcnt(0)" ::: "memory"); }
        __builtin_amdgcn_s_barrier();

        const short* Ac1 = Asm + (cur * 2 + 1) * 256 * 32;
        const short* Bc1 = Bsm + (cur * 2 + 1) * BN * 32;
        if (more) { stageA(nxt, 1, 0, t + 1); stageA(nxt, 1, 1, t + 1); }
#pragma unroll
        for (int m = 0; m < 4; ++m)
            a[m] = *(const bf16x8*)&Ac1[(wm * 128 + m * 16 + rr) * 32 + sl];
#pragma unroll
        for (int n = 0; n < NREP; ++n)
            b[n] = *(const bf16x8*)&Bc1[(wn * NSTRIP + n * 16 + rr) * 32 + sl];
        __builtin_amdgcn_s_setprio(1);
#pragma unroll
        for (int m = 0; m < 4; ++m)
#pragma unroll
            for (int n = 0; n < NREP; ++n)
                acc[m][n] = __builtin_amdgcn_mfma_f32_16x16x32_bf16(a[m], b[n], acc[m][n], 0, 0, 0);
        __builtin_amdgcn_s_setprio(0);
        if (more) {
#pragma unroll
            for (int jj = 0; jj < RB; ++jj) stageB(nxt, 1, jj, t + 1);
        }
#pragma unroll
        for (int m = 0; m < 4; ++m)
            a[m] = *(const bf16x8*)&Ac1[(wm * 128 + 64 + m * 16 + rr) * 32 + sl];
        __builtin_amdgcn_s_setprio(1);
#pragma unroll
        for (int m = 0; m < 4; ++m)
#pragma unroll
            for (int n = 0; n < NREP; ++n)
                acc[4 + m][n] = __builtin_amdgcn_mfma_f32_16x16x32_bf16(a[m], b[n], acc[4 + m][n], 0, 0, 0);
        __builtin_amdgcn_s_setprio(0);
    }

    const long zoff = (SPLITK > 1) ? (long)blockIdx.z * M * N : 0;
#pragma unroll
    for (int m = 0; m < 8; ++m) {
#pragma unroll
        for (int n = 0; n < NREP; ++n) {
#pragma unroll
            for (int r = 0; r < 4; ++r) {
                long row = m0 + wm * 128 + m * 16 + (lane >> 4) * 4 + r;
                long col = n0 + wn * NSTRIP + n * 16 + (lane & 15);
                float v = acc[m][n][r];
                if (MODE == 0) ((float*)Cout)[zoff + row * N + col] = v;
                else           ((unsigned short*)Cout)[zoff + row * N + col] = f2bf(v);
            }
        }
    }
}

// ============ x_proj split-K GEMM: 128x128 tile, K-slice 512, kz 0..3 ============
__global__ __launch_bounds__(256)
void gemm_xp(const unsigned short* __restrict__ A,
             const unsigned short* __restrict__ Bw,
             float* __restrict__ Cout)
{
    __shared__ short As[128 * 32];
    __shared__ short Bs[128 * 32];
    const int tid = threadIdx.x;
    const int wave = tid >> 6, lane = tid & 63;
    const int wm = wave >> 1, wn = wave & 1;
    const long m0 = (long)blockIdx.x * 128;
    const int kz = blockIdx.y;
    float* out = Cout + (long)kz * 8192 * 128;

    f32x4 acc[4][4] = {};

    const int srow = lane >> 2;
    const int g = (lane & 3) ^ ((srow >> 1) & 3);
    const int c0 = wave, c1 = wave + 4;

    for (int k0 = kz * 512; k0 < kz * 512 + 512; k0 += 32) {
        gload_lds16(A + (m0 + c0 * 16 + srow) * 2048L + k0 + g * 8, &As[c0 * 16 * 32]);
        gload_lds16(A + (m0 + c1 * 16 + srow) * 2048L + k0 + g * 8, &As[c1 * 16 * 32]);
        gload_lds16(Bw + (c0 * 16 + srow) * 2048L + k0 + g * 8, &Bs[c0 * 16 * 32]);
        gload_lds16(Bw + (c1 * 16 + srow) * 2048L + k0 + g * 8, &Bs[c1 * 16 * 32]);
        __syncthreads();

        const int rr = lane & 15;
        const int sl = ((lane >> 4) ^ ((rr >> 1) & 3)) * 8;
        bf16x8 af[4], bfr[4];
#pragma unroll
        for (int m = 0; m < 4; ++m)
            af[m] = *(const bf16x8*)&As[(wm * 64 + m * 16 + rr) * 32 + sl];
#pragma unroll
        for (int n = 0; n < 4; ++n)
            bfr[n] = *(const bf16x8*)&Bs[(wn * 64 + n * 16 + rr) * 32 + sl];
#pragma unroll
        for (int m = 0; m < 4; ++m)
#pragma unroll
            for (int n = 0; n < 4; ++n)
                acc[m][n] = __builtin_amdgcn_mfma_f32_16x16x32_bf16(af[m], bfr[n], acc[m][n], 0, 0, 0);
        __syncthreads();
    }

#pragma unroll
    for (int m = 0; m < 4; ++m)
#pragma unroll
        for (int n = 0; n < 4; ++n)
#pragma unroll
            for (int r = 0; r < 4; ++r) {
                long row = m0 + wm * 64 + m * 16 + (lane >> 4) * 4 + r;
                long col = wn * 64 + n * 16 + (lane & 15);
                out[row * 128 + col] = acc[m][n][r];
            }
}

// sum 4 K-partials -> dbc f32; cols < 64 also -> dt bf16
__global__ void reduce_dbc(const float* __restrict__ part,
                           float* __restrict__ dbc,
                           unsigned short* __restrict__ dt)
{
    const long i = (long)blockIdx.x * 256 + threadIdx.x;
    float s = part[i] + part[i + 1048576] + part[i + 2 * 1048576] + part[i + 3 * 1048576];
    dbc[i] = s;
    const int c = (int)(i & 127);
    if (c < 64) dt[(i >> 7) * 64 + c] = f2bf(s);
}

// ===== dt_proj: light 128x128 2-phase GEMM, K=64 =====
__global__ __launch_bounds__(256)
void gemm_dt(const unsigned short* __restrict__ A,
             const unsigned short* __restrict__ Bw,
             const float* __restrict__ bias,
             unsigned short* __restrict__ Cout)
{
    __shared__ short As[128 * 32];
    __shared__ short Bs[128 * 32];
    const int tid = threadIdx.x;
    const int wave = tid >> 6, lane = tid & 63;
    const int wm = wave >> 1, wn = wave & 1;
    const long m0 = (long)blockIdx.y * 128;
    const long n0 = (long)blockIdx.x * 128;

    f32x4 acc[4][4] = {};

    const int srow = lane >> 2;
    const int g = (lane & 3) ^ ((srow >> 1) & 3);
    const int c0 = wave, c1 = wave + 4;

    for (int k0 = 0; k0 < 64; k0 += 32) {
        gload_lds16(A + (m0 + c0 * 16 + srow) * 64L + k0 + g * 8, &As[c0 * 16 * 32]);
        gload_lds16(A + (m0 + c1 * 16 + srow) * 64L + k0 + g * 8, &As[c1 * 16 * 32]);
        gload_lds16(Bw + (n0 + c0 * 16 + srow) * 64L + k0 + g * 8, &Bs[c0 * 16 * 32]);
        gload_lds16(Bw + (n0 + c1 * 16 + srow) * 64L + k0 + g * 8, &Bs[c1 * 16 * 32]);
        __syncthreads();

        const int rr = lane & 15;
        const int sl = ((lane >> 4) ^ ((rr >> 1) & 3)) * 8;
        bf16x8 af[4], bfr[4];
#pragma unroll
        for (int m = 0; m < 4; ++m)
            af[m] = *(const bf16x8*)&As[(wm * 64 + m * 16 + rr) * 32 + sl];
#pragma unroll
        for (int n = 0; n < 4; ++n)
            bfr[n] = *(const bf16x8*)&Bs[(wn * 64 + n * 16 + rr) * 32 + sl];
#pragma unroll
        for (int m = 0; m < 4; ++m)
#pragma unroll
            for (int n = 0; n < 4; ++n)
                acc[m][n] = __builtin_amdgcn_mfma_f32_16x16x32_bf16(af[m], bfr[n], acc[m][n], 0, 0, 0);
        __syncthreads();
    }

#pragma unroll
    for (int m = 0; m < 4; ++m)
#pragma unroll
        for (int n = 0; n < 4; ++n)
#pragma unroll
            for (int r = 0; r < 4; ++r) {
                long row = m0 + wm * 64 + m * 16 + (lane >> 4) * 4 + r;
                long col = n0 + wn * 64 + n * 16 + (lane & 15);
                float v = acc[m][n][r] + bias[col];
                float sp = (v > 20.f) ? v : log1pf(__expf(v));
                Cout[row * 2048 + col] = f2bf(sp);
            }
}

// ---- all f32->bf16 operand conversions in ONE launch ----
__device__ inline void cvt4(const float* __restrict__ in, unsigned short* __restrict__ out, long i) {
    float4 v = ((const float4*)in)[i];
    unsigned lo = (unsigned)f2bf(v.x) | ((unsigned)f2bf(v.y) << 16);
    unsigned hi = (unsigned)f2bf(v.z) | ((unsigned)f2bf(v.w) << 16);
    ((uint2*)out)[i] = make_uint2(lo, hi);
}

__global__ void cvt_all(const float* __restrict__ inp, const float* __restrict__ w_in,
                        const float* __restrict__ w_xp, const float* __restrict__ w_dt,
                        const float* __restrict__ w_out,
                        unsigned short* __restrict__ o_inp, unsigned short* __restrict__ o_win,
                        unsigned short* __restrict__ o_wxp, unsigned short* __restrict__ o_wdt,
                        unsigned short* __restrict__ o_wout)
{
    const long t = (long)blockIdx.x * 256 + threadIdx.x;
    const long gs = (long)gridDim.x * 256;
    for (long i = t; i < 8388608 / 4; i += gs) cvt4(inp, o_inp, i);
    for (long i = t; i < 4194304 / 4; i += gs) cvt4(w_in, o_win, i);
    for (long i = t; i < 2097152 / 4; i += gs) cvt4(w_out, o_wout, i);
    for (long i = t; i < 131072 / 4; i += gs) cvt4(w_dt, o_wdt, i);
    for (long i = t; i < 262144 / 4; i += gs) {
        const int r = (int)(i >> 9);
        if (r < 80) cvt4(w_xp, o_wxp, i);
        else ((uint2*)o_wxp)[i] = make_uint2(0u, 0u);
    }
}

// depthwise causal conv (K=4) + bias + silu; 4 channels per thread (uint2 I/O).
__global__ void conv_silu_k(const unsigned short* __restrict__ xz,
                            const float* __restrict__ cw,
                            const float* __restrict__ cb,
                            unsigned short* __restrict__ xc)
{
    const int eq = blockIdx.y * 256 + threadIdx.x;
    const int e0 = eq * 4;
    const int b = blockIdx.z;
    const int l0 = blockIdx.x * 32;
    float w0[4], w1[4], w2[4], w3[4], bi[4];
#pragma unroll
    for (int c = 0; c < 4; ++c) {
        w0[c] = cw[(e0 + c) * 4 + 0]; w1[c] = cw[(e0 + c) * 4 + 1];
        w2[c] = cw[(e0 + c) * 4 + 2]; w3[c] = cw[(e0 + c) * 4 + 3];
        bi[c] = cb[e0 + c];
    }
    const uint2* xrow = (const uint2*)(xz + (long)b * LL * 4096) + eq;
    uint2* orow = (uint2*)(xc + (long)b * LL * 2048) + eq;

    float s3[4] = {}, s2[4] = {}, s1[4] = {};
    auto unpack = [](uint2 u, float* f) {
        f[0] = bf2f(u.x & 0xffff); f[1] = bf2f(u.x >> 16);
        f[2] = bf2f(u.y & 0xffff); f[3] = bf2f(u.y >> 16);
    };
    if (l0 >= 3) { float f[4]; unpack(xrow[(long)(l0 - 3) * 1024], f);
#pragma unroll
        for (int c = 0; c < 4; ++c) s3[c] = f[c]; }
    if (l0 >= 2) { float f[4]; unpack(xrow[(long)(l0 - 2) * 1024], f);
#pragma unroll
        for (int c = 0; c < 4; ++c) s2[c] = f[c]; }
    if (l0 >= 1) { float f[4]; unpack(xrow[(long)(l0 - 1) * 1024], f);
#pragma unroll
        for (int c = 0; c < 4; ++c) s1[c] = f[c]; }
#pragma unroll 2
    for (int l = l0; l < l0 + 32; ++l) {
        float x[4]; unpack(xrow[(long)l * 1024], x);
        unsigned short o[4];
#pragma unroll
        for (int c = 0; c < 4; ++c) {
            float v = bi[c] + w0[c] * s3[c] + w1[c] * s2[c] + w2[c] * s1[c] + w3[c] * x[c];
            float s = v / (1.f + __expf(-v));
            o[c] = f2bf(s);
            s3[c] = s2[c]; s2[c] = s1[c]; s1[c] = x[c];
        }
        uint2 ov;
        ov.x = (unsigned)o[0] | ((unsigned)o[1] << 16);
        ov.y = (unsigned)o[2] | ((unsigned)o[3] << 16);
        orow[(long)l * 512] = ov;
    }
}

// ------- chunked parallel SSM scan, 2 channels/thread (NC=64, CH=32) -------
__global__ __launch_bounds__(256)
void scan_local(const unsigned short* __restrict__ delta,
                const unsigned short* __restrict__ xconv,
                const float* __restrict__ dbc,
                const float* __restrict__ A_log,
                float* __restrict__ hend, float* __restrict__ Ssum)
{
    const int ep = blockIdx.x * 256 + threadIdx.x;
    const int e0 = ep * 2;
    const int c = blockIdx.y, b = blockIdx.z;
    const int l0 = c * CH;
    float An[16];
#pragma unroll
    for (int n = 0; n < 16; ++n) An[n] = -__expf(A_log[e0 * 8 + n]);
    float h[16] = {};
    float S0 = 0.f, S1 = 0.f;
    const unsigned* drow = (const unsigned*)(delta + ((long)b * LL + l0) * EE) + ep;
    const unsigned* urow = (const unsigned*)(xconv + ((long)b * LL + l0) * EE) + ep;
    const float* bc = dbc + ((long)b * LL + l0) * 128;
#pragma unroll 2
    for (int l = 0; l < CH; ++l) {
        unsigned dv = drow[(long)l * 1024];
        unsigned uv = urow[(long)l * 1024];
        float d0 = bf2f(dv & 0xffff), d1 = bf2f(dv >> 16);
        float u0 = bf2f(uv & 0xffff), u1 = bf2f(uv >> 16);
        float du0 = d0 * u0, du1 = d1 * u1;
        S0 += d0; S1 += d1;
#pragma unroll
        for (int n = 0; n < 8; ++n) {
            float bn = bc[l * 128 + 64 + n];
            h[n]     = h[n]     * __expf(d0 * An[n])     + du0 * bn;
            h[8 + n] = h[8 + n] * __expf(d1 * An[8 + n]) + du1 * bn;
        }
    }
    const long o = ((long)b * NC + c) * EE + e0;
#pragma unroll
    for (int n = 0; n < 8; ++n) { hend[o * 8 + n] = h[n]; hend[(o + 1) * 8 + n] = h[8 + n]; }
    Ssum[o] = S0; Ssum[o + 1] = S1;
}

// combine parallelized over (b,e,n): 65536 threads = 256 blocks.
__global__ __launch_bounds__(256)
void scan_combine(const float* __restrict__ hend, const float* __restrict__ Ssum,
                  const float* __restrict__ A_log, float* __restrict__ hin)
{
    const int t = blockIdx.x * 256 + threadIdx.x;
    const int n = t & 7;
    const int be = t >> 3;
    const int b = be >> 11, e = be & 2047;
    const float An = -__expf(A_log[e * 8 + n]);
    float h = 0.f;
    for (int c = 0; c < NC; ++c) {
        const long o = ((long)b * NC + c) * EE + e;
        hin[o * 8 + n] = h;
        h = h * __expf(An * Ssum[o]) + hend[o * 8 + n];
    }
}

__global__ __launch_bounds__(256)
void scan_final(const unsigned short* __restrict__ delta,
                const unsigned short* __restrict__ xconv,
                const float* __restrict__ dbc,
                const unsigned short* __restrict__ xz,
                const float* __restrict__ A_log,
                const float* __restrict__ Dparam,
                const float* __restrict__ hin,
                unsigned short* __restrict__ yg)
{
    const int ep = blockIdx.x * 256 + threadIdx.x;
    const int e0 = ep * 2;
    const int c = blockIdx.y, b = blockIdx.z;
    const int l0 = c * CH;
    float An[16];
#pragma unroll
    for (int n = 0; n < 16; ++n) An[n] = -__expf(A_log[e0 * 8 + n]);
    const float Dp0 = Dparam[e0], Dp1 = Dparam[e0 + 1];
    float h[16];
    const long o = ((long)b * NC + c) * EE + e0;
#pragma unroll
    for (int n = 0; n < 8; ++n) { h[n] = hin[o * 8 + n]; h[8 + n] = hin[(o + 1) * 8 + n]; }
    const unsigned* drow = (const unsigned*)(delta + ((long)b * LL + l0) * EE) + ep;
    const unsigned* urow = (const unsigned*)(xconv + ((long)b * LL + l0) * EE) + ep;
    const unsigned* zrow = (const unsigned*)(xz + ((long)b * LL + l0) * 4096 + 2048) + ep;
    const float* bc = dbc + ((long)b * LL + l0) * 128;
    unsigned* yrow = (unsigned*)(yg + ((long)b * LL + l0) * EE) + ep;
#pragma unroll 2
    for (int l = 0; l < CH; ++l) {
        unsigned dv = drow[(long)l * 1024];
        unsigned uv = urow[(long)l * 1024];
        float d0 = bf2f(dv & 0xffff), d1 = bf2f(dv >> 16);
        float u0 = bf2f(uv & 0xffff), u1 = bf2f(uv >> 16);
        float du0 = d0 * u0, du1 = d1 * u1;
        float y0 = 0.f, y1 = 0.f;
#pragma unroll
        for (int n = 0; n < 8; ++n) {
            float bn = bc[l * 128 + 64 + n];
            float cn = bc[l * 128 + 72 + n];
            h[n]     = h[n]     * __expf(d0 * An[n])     + du0 * bn;
            h[8 + n] = h[8 + n] * __expf(d1 * An[8 + n]) + du1 * bn;
            y0 += h[n] * cn;
            y1 += h[8 + n] * cn;
        }
        y0 += u0 * Dp0; y1 += u1 * Dp1;
        unsigned zv = zrow[(long)l * 2048];
        float z0 = bf2f(zv & 0xffff), z1 = bf2f(zv >> 16);
        float g0 = z0 / (1.f + __expf(-z0));
        float g1 = z1 / (1.f + __expf(-z1));
        yrow[(long)l * 1024] = (unsigned)f2bf(y0 * g0) | ((unsigned)f2bf(y1 * g1) << 16);
    }
}

// RMSNorm over sum of 2 bf16 K-partials: one wave per row. grid 2048 x 256.
__global__ __launch_bounds__(256)
void rmsnorm_k(const unsigned short* __restrict__ p0,
               const unsigned short* __restrict__ p1,
               const float* __restrict__ w,
               float* __restrict__ out)
{
    const int wave = threadIdx.x >> 6, lane = threadIdx.x & 63;
    const long row = (long)blockIdx.x * 4 + wave;
    const uint4* pa = (const uint4*)(p0 + row * 1024) + lane * 2;
    const uint4* pb = (const uint4*)(p1 + row * 1024) + lane * 2;
    uint4 a0 = pa[0], a1 = pa[1], b0 = pb[0], b1 = pb[1];
    float x[16];
    auto up = [](unsigned ua, unsigned ub, float* f) {
        f[0] = bf2f(ua & 0xffff) + bf2f(ub & 0xffff);
        f[1] = bf2f(ua >> 16) + bf2f(ub >> 16);
    };
    up(a0.x, b0.x, &x[0]);  up(a0.y, b0.y, &x[2]);
    up(a0.z, b0.z, &x[4]);  up(a0.w, b0.w, &x[6]);
    up(a1.x, b1.x, &x[8]);  up(a1.y, b1.y, &x[10]);
    up(a1.z, b1.z, &x[12]); up(a1.w, b1.w, &x[14]);
    float ss = 0.f;
#pragma unroll
    for (int i = 0; i < 16; ++i) ss += x[i] * x[i];
#pragma unroll
    for (int m = 32; m >= 1; m >>= 1) ss += __shfl_xor(ss, m, 64);
    const float sc = rsqrtf(ss * (1.f / 1024.f) + 1e-5f);
    const float4* wv = (const float4*)w + lane * 4;
    float* op = out + row * 1024 + lane * 16;
#pragma unroll
    for (int q = 0; q < 4; ++q) {
        float4 ww = wv[q];
        float4 o;
        o.x = x[q * 4 + 0] * sc * ww.x;
        o.y = x[q * 4 + 1] * sc * ww.y;
        o.z = x[q * 4 + 2] * sc * ww.z;
        o.w = x[q * 4 + 3] * sc * ww.w;
        ((float4*)op)[q] = o;
    }
}

extern "C" void kernel_launch(void* const* d_in, const int* in_sizes, int n_in,
                              void* d_out, int out_size, void* d_ws, size_t ws_size,
                              hipStream_t stream)
{
    const float* inp   = (const float*)d_in[0];
    const float* w_in  = (const float*)d_in[1];
    const float* convw = (const float*)d_in[2];
    const float* convb = (const float*)d_in[3];
    const float* w_xp  = (const float*)d_in[4];
    const float* w_dt  = (const float*)d_in[5];
    const float* b_dt  = (const float*)d_in[6];
    const float* A_log = (const float*)d_in[7];
    const float* Dp    = (const float*)d_in[8];
    const float* w_out = (const float*)d_in[9];
    const float* rmsw  = (const float*)d_in[10];

    char* ws = (char*)d_ws;
    const size_t MB = 1024 * 1024;
    unsigned short* inp_bf   = (unsigned short*)(ws + 0);        // 16MB (dead after GEMM1)
    unsigned short* win_bf   = (unsigned short*)(ws + 16 * MB);  // 8MB  (dead after GEMM1)
    unsigned short* xz_bf    = (unsigned short*)(ws + 24 * MB);  // 64MB (live until scan_final)
    unsigned short* xconv_bf = (unsigned short*)(ws + 88 * MB);  // 32MB
    unsigned short* wxp_bf   = (unsigned short*)(ws + 120 * MB); // 0.5MB
    float*          dbc      = (float*)(ws + 121 * MB);          // 4MB
    unsigned short* dt_bf    = (unsigned short*)(ws + 125 * MB); // 1MB
    unsigned short* wdt_bf   = (unsigned short*)(ws + 126 * MB); // 0.25MB
    unsigned short* delta_bf = (unsigned short*)(ws + 127 * MB); // 32MB
    unsigned short* yg_bf    = (unsigned short*)(ws + 191 * MB); // 32MB
    unsigned short* wout_bf  = (unsigned short*)(ws + 223 * MB); // 4MB
    float*          dbc_part = (float*)(ws + 159 * MB);          // 16MB (xp partials)
    float*          hend     = (float*)(ws + 159 * MB);          // 16MB (after reduce)
    float*          hin      = (float*)(ws + 175 * MB);          // 16MB
    float*          Ssum     = (float*)(ws + 0);                 // 2MB  (dead after combine)
    unsigned short* out_part = (unsigned short*)(ws + 0);        // 32MB: 2 bf16 K-partials
                                                                 // (over dead inp/win/xz head)

    hipFuncSetAttribute((const void*)gemm8p<1, 256, 4, 1>, hipFuncAttributeMaxDynamicSharedMemorySize, 131072);
    hipFuncSetAttribute((const void*)gemm8p<1, 256, 4, 2>, hipFuncAttributeMaxDynamicSharedMemorySize, 131072);

    cvt_all<<<2048, 256, 0, stream>>>(inp, w_in, w_xp, w_dt, w_out,
                                      inp_bf, win_bf, wxp_bf, wdt_bf, wout_bf);

    // xz = inp @ in_proj_w^T (8192 x 4096, K=1024) -> bf16
    gemm8p<1, 256, 4, 1><<<dim3(16, 32), 512, 131072, stream>>>(inp_bf, win_bf, xz_bf, 8192, 4096, 1024);
    // depthwise causal conv + silu (4 channels/thread)
    conv_silu_k<<<dim3(64, 2, 4), 256, 0, stream>>>(xz_bf, convw, convb, xconv_bf);
    // dbc partials: xconv @ x_proj_w^T split-K (4 x 512)
    gemm_xp<<<dim3(64, 4), 256, 0, stream>>>(xconv_bf, wxp_bf, dbc_part);
    // reduce partials -> dbc f32 + dt bf16
    reduce_dbc<<<4096, 256, 0, stream>>>(dbc_part, dbc, dt_bf);
    // delta = softplus(dt @ dt_proj_w^T + b) -> bf16
    gemm_dt<<<dim3(16, 64), 256, 0, stream>>>(dt_bf, wdt_bf, b_dt, delta_bf);
    // chunked parallel SSM scan
    scan_local<<<dim3(4, NC, 4), 256, 0, stream>>>(delta_bf, xconv_bf, dbc, A_log, hend, Ssum);
    scan_combine<<<256, 256, 0, stream>>>(hend, Ssum, A_log, hin);
    scan_final<<<dim3(4, NC, 4), 256, 0, stream>>>(delta_bf, xconv_bf, dbc, xz_bf, A_log, Dp, hin, yg_bf);
    // out_proj split-K=2: BN=256 tile, grid (4,32,2) = 256 blocks = 1/CU, bf16 partials
    gemm8p<1, 256, 4, 2><<<dim3(4, 32, 2), 512, 131072, stream>>>(yg_bf, wout_bf, out_part, 8192, 1024, 2048);
    // RMSNorm over summed partials (bf16 in x2, f32 out), one wave per row
    rmsnorm_k<<<2048, 256, 0, stream>>>(out_part, out_part + (long)8192 * 1024, rmsw, (float*)d_out);
}